// Round 2
// baseline (1714.697 us; speedup 1.0000x reference)
//
#include <hip/hip_runtime.h>

// HGWaveNet fused: out = hist2 @ K0^T + (norm_in ⊙ agg) @ (gc_weight @ K1^T) + c
// where agg[d] = sum_{e: dst[e]=d} norm_out[src[e]] * x[src[e]]

__global__ void degree_kernel(const int* __restrict__ src, const int* __restrict__ dst,
                              int* __restrict__ dego, int* __restrict__ degi, int n_edges) {
    int stride = gridDim.x * blockDim.x;
    for (int i = blockIdx.x * blockDim.x + threadIdx.x; i < n_edges; i += stride) {
        atomicAdd(&dego[src[i]], 1);
        atomicAdd(&degi[dst[i]], 1);
    }
}

__global__ void norm_kernel(const int* __restrict__ dego, const int* __restrict__ degi,
                            float* __restrict__ norm_out, float* __restrict__ norm_in, int n) {
    int i = blockIdx.x * blockDim.x + threadIdx.x;
    if (i < n) {
        norm_out[i] = rsqrtf(fmaxf((float)dego[i], 1.0f));
        norm_in[i]  = rsqrtf(fmaxf((float)degi[i], 1.0f));
    }
}

// grid 128 (i), block 128 (o).
// Bmat[i][o]        = K0[o,i] = tcn[o*384 + i*3 + 0]           (i < 128)
// Bmat[128+i][o]    = M[i][o] = sum_j gcw[i,j] * tcn[o*384+j*3+1]
// cvec[o]           = tcnb[o] + sum_j tcn[o*384+j*3+1] * gcb[j]
__global__ void prep_kernel(const float* __restrict__ gcw, const float* __restrict__ gcb,
                            const float* __restrict__ tcn, const float* __restrict__ tcnb,
                            float* __restrict__ Bmat, float* __restrict__ cvec) {
    int i = blockIdx.x;
    int o = threadIdx.x;
    float m = 0.f;
    for (int j = 0; j < 128; ++j)
        m += gcw[i * 128 + j] * tcn[o * 384 + j * 3 + 1];
    Bmat[(128 + i) * 128 + o] = m;
    Bmat[i * 128 + o] = tcn[o * 384 + i * 3 + 0];
    if (i == 0) {
        float c = tcnb[o];
        for (int j = 0; j < 128; ++j)
            c += tcn[o * 384 + j * 3 + 1] * gcb[j];
        cvec[o] = c;
    }
}

// One wave (64 lanes) per edge iteration; lane handles 2 consecutive floats.
__global__ void scatter_kernel(const float* __restrict__ x, const int* __restrict__ src,
                               const int* __restrict__ dst, const float* __restrict__ norm_out,
                               float* __restrict__ agg, int n_edges) {
    int gtid = blockIdx.x * blockDim.x + threadIdx.x;
    int wave = gtid >> 6;
    int lane = threadIdx.x & 63;
    int n_waves = (gridDim.x * blockDim.x) >> 6;
    for (int e = wave; e < n_edges; e += n_waves) {
        int s = src[e];
        int d = dst[e];
        float no = norm_out[s];
        const float2 v = *reinterpret_cast<const float2*>(x + (size_t)s * 128 + lane * 2);
        float* p = agg + (size_t)d * 128 + lane * 2;
        atomicAdd(p + 0, v.x * no);
        atomicAdd(p + 1, v.y * no);
    }
}

// Tiled fp32 GEMM: out[n,o] = cvec[o] + sum_{i<128} hist2[n,i]*Bmat[i][o]
//                             + sum_{i<128} norm_in[n]*agg[n,i]*Bmat[128+i][o]
// agg lives in `outagg` (= d_out) and is overwritten in place by this block's rows.
__global__ __launch_bounds__(256) void gemm_kernel(const float* __restrict__ hist2,
                                                   float* __restrict__ outagg,
                                                   const float* __restrict__ norm_in,
                                                   const float* __restrict__ Bmat,
                                                   const float* __restrict__ cvec, int n) {
    __shared__ float As[64][17];   // +1 pad: avoids bank conflicts on column reads
    __shared__ float Bs[16][128];
    const int t = threadIdx.x;
    const int tcol = t & 15;   // cols tcol*8 .. +7
    const int trow = t >> 4;   // rows trow*4 .. +3
    const int block_row = blockIdx.x * 64;

    float acc[4][8];
#pragma unroll
    for (int j = 0; j < 4; ++j)
#pragma unroll
        for (int m = 0; m < 8; ++m) acc[j][m] = 0.f;

    for (int kk = 0; kk < 256; kk += 16) {
        // stage A: 64 rows x 16 k, one float4 per thread
        {
            int r = t >> 2;
            int k4 = (t & 3) << 2;
            int row = block_row + r;
            float4 v = make_float4(0.f, 0.f, 0.f, 0.f);
            if (row < n) {
                if (kk < 128) {
                    v = *reinterpret_cast<const float4*>(hist2 + (size_t)row * 128 + kk + k4);
                } else {
                    v = *reinterpret_cast<const float4*>(outagg + (size_t)row * 128 + (kk - 128) + k4);
                    float ni = norm_in[row];
                    v.x *= ni; v.y *= ni; v.z *= ni; v.w *= ni;
                }
            }
            As[r][k4 + 0] = v.x; As[r][k4 + 1] = v.y;
            As[r][k4 + 2] = v.z; As[r][k4 + 3] = v.w;
        }
        // stage B: 16 x 128 floats = 512 float4, 2 per thread
        {
#pragma unroll
            for (int rep = 0; rep < 2; ++rep) {
                int idx = t + rep * 256;
                int k = idx >> 5;
                int o4 = (idx & 31) << 2;
                const float4 v = *reinterpret_cast<const float4*>(Bmat + (size_t)(kk + k) * 128 + o4);
                *reinterpret_cast<float4*>(&Bs[k][o4]) = v;
            }
        }
        __syncthreads();
#pragma unroll
        for (int k = 0; k < 16; ++k) {
            float a0 = As[trow * 4 + 0][k];
            float a1 = As[trow * 4 + 1][k];
            float a2 = As[trow * 4 + 2][k];
            float a3 = As[trow * 4 + 3][k];
            float4 b0 = *reinterpret_cast<const float4*>(&Bs[k][tcol * 8]);
            float4 b1 = *reinterpret_cast<const float4*>(&Bs[k][tcol * 8 + 4]);
            float b[8] = {b0.x, b0.y, b0.z, b0.w, b1.x, b1.y, b1.z, b1.w};
#pragma unroll
            for (int m = 0; m < 8; ++m) {
                acc[0][m] = fmaf(a0, b[m], acc[0][m]);
                acc[1][m] = fmaf(a1, b[m], acc[1][m]);
                acc[2][m] = fmaf(a2, b[m], acc[2][m]);
                acc[3][m] = fmaf(a3, b[m], acc[3][m]);
            }
        }
        __syncthreads();
    }
    // epilogue — all global reads of outagg rows for this block are done
    float cv[8];
#pragma unroll
    for (int m = 0; m < 8; ++m) cv[m] = cvec[tcol * 8 + m];
#pragma unroll
    for (int j = 0; j < 4; ++j) {
        int row = block_row + trow * 4 + j;
        if (row < n) {
            float4 w0 = make_float4(acc[j][0] + cv[0], acc[j][1] + cv[1],
                                    acc[j][2] + cv[2], acc[j][3] + cv[3]);
            float4 w1 = make_float4(acc[j][4] + cv[4], acc[j][5] + cv[5],
                                    acc[j][6] + cv[6], acc[j][7] + cv[7]);
            *reinterpret_cast<float4*>(outagg + (size_t)row * 128 + tcol * 8) = w0;
            *reinterpret_cast<float4*>(outagg + (size_t)row * 128 + tcol * 8 + 4) = w1;
        }
    }
}

extern "C" void kernel_launch(void* const* d_in, const int* in_sizes, int n_in,
                              void* d_out, int out_size, void* d_ws, size_t ws_size,
                              hipStream_t stream) {
    const float* x     = (const float*)d_in[0];
    const float* gcw   = (const float*)d_in[1];
    const float* gcb   = (const float*)d_in[2];
    const float* tcn   = (const float*)d_in[3];
    const float* tcnb  = (const float*)d_in[4];
    const float* hist2 = (const float*)d_in[7];   // hist0/hist1 are dead
    const int*   src   = (const int*)d_in[8];
    const int*   dst   = (const int*)d_in[9];
    float* out = (float*)d_out;

    const int n = in_sizes[0] / 128;
    const int e = in_sizes[8];

    auto align256 = [](size_t v) { return (v + 255) & ~(size_t)255; };
    char* ws = (char*)d_ws;
    int*   dego     = (int*)ws;    ws += align256((size_t)n * 4);
    int*   degi     = (int*)ws;    ws += align256((size_t)n * 4);
    float* norm_out = (float*)ws;  ws += align256((size_t)n * 4);
    float* norm_in  = (float*)ws;  ws += align256((size_t)n * 4);
    float* Bmat     = (float*)ws;  ws += align256((size_t)256 * 128 * 4);
    float* cvec     = (float*)ws;  ws += align256((size_t)128 * 4);

    // zero degree histograms and the agg accumulator (d_out doubles as agg)
    hipMemsetAsync(dego, 0, align256((size_t)n * 4) * 2, stream);
    hipMemsetAsync(out, 0, (size_t)out_size * sizeof(float), stream);

    degree_kernel<<<2048, 256, 0, stream>>>(src, dst, dego, degi, e);
    norm_kernel<<<(n + 255) / 256, 256, 0, stream>>>(dego, degi, norm_out, norm_in, n);
    prep_kernel<<<128, 128, 0, stream>>>(gcw, gcb, tcn, tcnb, Bmat, cvec);
    scatter_kernel<<<4096, 256, 0, stream>>>(x, src, dst, norm_out, out, e);
    gemm_kernel<<<(n + 63) / 64, 256, 0, stream>>>(hist2, out, norm_in, Bmat, cvec, n);
}

// Round 3
// 797.736 us; speedup vs baseline: 2.1495x; 2.1495x over previous
//
#include <hip/hip_runtime.h>

// out = hist2 @ K0^T + (norm_in ⊙ agg) @ (gc_weight @ K1^T) + c
// agg[d] = sum_{e: dst[e]=d} norm_out[src[e]] * x[src[e]]
// Round 3: dst-CSR (counting sort) + gather-side aggregation — no fp32 atomics.

__global__ void degree_kernel(const int* __restrict__ src, const int* __restrict__ dst,
                              int* __restrict__ dego, int* __restrict__ degi, int n_edges) {
    int stride = gridDim.x * blockDim.x;
    for (int i = blockIdx.x * blockDim.x + threadIdx.x; i < n_edges; i += stride) {
        atomicAdd(&dego[src[i]], 1);
        atomicAdd(&degi[dst[i]], 1);
    }
}

__global__ void norm_kernel(const int* __restrict__ dego, const int* __restrict__ degi,
                            float* __restrict__ norm_out, float* __restrict__ norm_in, int n) {
    int i = blockIdx.x * blockDim.x + threadIdx.x;
    if (i < n) {
        norm_out[i] = rsqrtf(fmaxf((float)dego[i], 1.0f));
        norm_in[i]  = rsqrtf(fmaxf((float)degi[i], 1.0f));
    }
}

// Single-block exclusive scan of degi[0..n) -> rowptr[0..n]
__global__ __launch_bounds__(1024) void scan_kernel(const int* __restrict__ degi,
                                                    int* __restrict__ rowptr, int n) {
    __shared__ int sums[1024];
    const int t = threadIdx.x;
    const int chunk = (n + 1023) / 1024;
    const int begin = t * chunk;
    const int end = min(begin + chunk, n);
    int s = 0;
    for (int i = begin; i < end; ++i) s += degi[i];
    sums[t] = s;
    __syncthreads();
    // Hillis–Steele inclusive scan
    for (int off = 1; off < 1024; off <<= 1) {
        int v = (t >= off) ? sums[t - off] : 0;
        __syncthreads();
        if (t >= off) sums[t] += v;
        __syncthreads();
    }
    int run = (t == 0) ? 0 : sums[t - 1];   // exclusive prefix of this chunk
    for (int i = begin; i < end; ++i) { rowptr[i] = run; run += degi[i]; }
    if (t == 1023) rowptr[n] = sums[1023];
}

// csr_src[rowptr[dst[e]] + k] = src[e]
__global__ void fill_kernel(const int* __restrict__ src, const int* __restrict__ dst,
                            const int* __restrict__ rowptr, int* __restrict__ cursor,
                            int* __restrict__ csr_src, int n_edges) {
    int stride = gridDim.x * blockDim.x;
    for (int i = blockIdx.x * blockDim.x + threadIdx.x; i < n_edges; i += stride) {
        int d = dst[i];
        int ofs = atomicAdd(&cursor[d], 1);
        csr_src[rowptr[d] + ofs] = src[i];
    }
}

// One wave per dst node; lane owns 2 consecutive floats. Writes norm_in-scaled agg.
__global__ void gather_kernel(const float* __restrict__ x, const int* __restrict__ csr_src,
                              const int* __restrict__ rowptr, const float* __restrict__ norm_out,
                              const float* __restrict__ norm_in, float* __restrict__ agg, int n) {
    int gtid = blockIdx.x * blockDim.x + threadIdx.x;
    int wave = gtid >> 6;
    int lane = threadIdx.x & 63;
    int n_waves = (gridDim.x * blockDim.x) >> 6;
    for (int d = wave; d < n; d += n_waves) {
        int s0 = rowptr[d];
        int s1 = rowptr[d + 1];
        float2 acc0 = {0.f, 0.f}, acc1 = {0.f, 0.f};
        int i = s0;
        for (; i + 1 < s1; i += 2) {
            int sa = csr_src[i];
            int sb = csr_src[i + 1];
            float na = norm_out[sa];
            float nb = norm_out[sb];
            float2 va = *reinterpret_cast<const float2*>(x + (size_t)sa * 128 + lane * 2);
            float2 vb = *reinterpret_cast<const float2*>(x + (size_t)sb * 128 + lane * 2);
            acc0.x = fmaf(va.x, na, acc0.x);
            acc0.y = fmaf(va.y, na, acc0.y);
            acc1.x = fmaf(vb.x, nb, acc1.x);
            acc1.y = fmaf(vb.y, nb, acc1.y);
        }
        if (i < s1) {
            int sa = csr_src[i];
            float na = norm_out[sa];
            float2 va = *reinterpret_cast<const float2*>(x + (size_t)sa * 128 + lane * 2);
            acc0.x = fmaf(va.x, na, acc0.x);
            acc0.y = fmaf(va.y, na, acc0.y);
        }
        float ni = norm_in[d];
        float2 r = {(acc0.x + acc1.x) * ni, (acc0.y + acc1.y) * ni};
        *reinterpret_cast<float2*>(agg + (size_t)d * 128 + lane * 2) = r;
    }
}

// Bmat[i][o] = K0[o,i]; Bmat[128+i][o] = sum_j gcw[i,j]*K1[o,j]; cvec[o] = tcnb[o] + K1[o,:]·gcb
__global__ void prep_kernel(const float* __restrict__ gcw, const float* __restrict__ gcb,
                            const float* __restrict__ tcn, const float* __restrict__ tcnb,
                            float* __restrict__ Bmat, float* __restrict__ cvec) {
    int i = blockIdx.x;
    int o = threadIdx.x;
    float m = 0.f;
    for (int j = 0; j < 128; ++j)
        m += gcw[i * 128 + j] * tcn[o * 384 + j * 3 + 1];
    Bmat[(128 + i) * 128 + o] = m;
    Bmat[i * 128 + o] = tcn[o * 384 + i * 3 + 0];
    if (i == 0) {
        float c = tcnb[o];
        for (int j = 0; j < 128; ++j)
            c += tcn[o * 384 + j * 3 + 1] * gcb[j];
        cvec[o] = c;
    }
}

// out[n,o] = cvec[o] + sum_i hist2[n,i]*Bmat[i][o] + sum_i agg[n,i]*Bmat[128+i][o]
// agg lives in d_out, overwritten in place by this block's rows.
__global__ __launch_bounds__(256) void gemm_kernel(const float* __restrict__ hist2,
                                                   float* __restrict__ outagg,
                                                   const float* __restrict__ Bmat,
                                                   const float* __restrict__ cvec, int n) {
    __shared__ float As[64][17];
    __shared__ float Bs[16][128];
    const int t = threadIdx.x;
    const int tcol = t & 15;
    const int trow = t >> 4;
    const int block_row = blockIdx.x * 64;

    float acc[4][8];
#pragma unroll
    for (int j = 0; j < 4; ++j)
#pragma unroll
        for (int m = 0; m < 8; ++m) acc[j][m] = 0.f;

    for (int kk = 0; kk < 256; kk += 16) {
        {
            int r = t >> 2;
            int k4 = (t & 3) << 2;
            int row = block_row + r;
            float4 v = make_float4(0.f, 0.f, 0.f, 0.f);
            if (row < n) {
                if (kk < 128)
                    v = *reinterpret_cast<const float4*>(hist2 + (size_t)row * 128 + kk + k4);
                else
                    v = *reinterpret_cast<const float4*>(outagg + (size_t)row * 128 + (kk - 128) + k4);
            }
            As[r][k4 + 0] = v.x; As[r][k4 + 1] = v.y;
            As[r][k4 + 2] = v.z; As[r][k4 + 3] = v.w;
        }
        {
#pragma unroll
            for (int rep = 0; rep < 2; ++rep) {
                int idx = t + rep * 256;
                int k = idx >> 5;
                int o4 = (idx & 31) << 2;
                const float4 v = *reinterpret_cast<const float4*>(Bmat + (size_t)(kk + k) * 128 + o4);
                *reinterpret_cast<float4*>(&Bs[k][o4]) = v;
            }
        }
        __syncthreads();
#pragma unroll
        for (int k = 0; k < 16; ++k) {
            float a0 = As[trow * 4 + 0][k];
            float a1 = As[trow * 4 + 1][k];
            float a2 = As[trow * 4 + 2][k];
            float a3 = As[trow * 4 + 3][k];
            float4 b0 = *reinterpret_cast<const float4*>(&Bs[k][tcol * 8]);
            float4 b1 = *reinterpret_cast<const float4*>(&Bs[k][tcol * 8 + 4]);
            float b[8] = {b0.x, b0.y, b0.z, b0.w, b1.x, b1.y, b1.z, b1.w};
#pragma unroll
            for (int m = 0; m < 8; ++m) {
                acc[0][m] = fmaf(a0, b[m], acc[0][m]);
                acc[1][m] = fmaf(a1, b[m], acc[1][m]);
                acc[2][m] = fmaf(a2, b[m], acc[2][m]);
                acc[3][m] = fmaf(a3, b[m], acc[3][m]);
            }
        }
        __syncthreads();
    }
    float cv[8];
#pragma unroll
    for (int m = 0; m < 8; ++m) cv[m] = cvec[tcol * 8 + m];
#pragma unroll
    for (int j = 0; j < 4; ++j) {
        int row = block_row + trow * 4 + j;
        if (row < n) {
            float4 w0 = make_float4(acc[j][0] + cv[0], acc[j][1] + cv[1],
                                    acc[j][2] + cv[2], acc[j][3] + cv[3]);
            float4 w1 = make_float4(acc[j][4] + cv[4], acc[j][5] + cv[5],
                                    acc[j][6] + cv[6], acc[j][7] + cv[7]);
            *reinterpret_cast<float4*>(outagg + (size_t)row * 128 + tcol * 8) = w0;
            *reinterpret_cast<float4*>(outagg + (size_t)row * 128 + tcol * 8 + 4) = w1;
        }
    }
}

extern "C" void kernel_launch(void* const* d_in, const int* in_sizes, int n_in,
                              void* d_out, int out_size, void* d_ws, size_t ws_size,
                              hipStream_t stream) {
    const float* x     = (const float*)d_in[0];
    const float* gcw   = (const float*)d_in[1];
    const float* gcb   = (const float*)d_in[2];
    const float* tcn   = (const float*)d_in[3];
    const float* tcnb  = (const float*)d_in[4];
    const float* hist2 = (const float*)d_in[7];   // hist0/hist1 are dead
    const int*   src   = (const int*)d_in[8];
    const int*   dst   = (const int*)d_in[9];
    float* out = (float*)d_out;

    const int n = in_sizes[0] / 128;
    const int e = in_sizes[8];

    auto align256 = [](size_t v) { return (v + 255) & ~(size_t)255; };
    char* ws = (char*)d_ws;
    int*   dego     = (int*)ws;    ws += align256((size_t)n * 4);
    int*   degi     = (int*)ws;    ws += align256((size_t)n * 4);
    int*   cursor   = (int*)ws;    ws += align256((size_t)n * 4);
    float* norm_out = (float*)ws;  ws += align256((size_t)n * 4);
    float* norm_in  = (float*)ws;  ws += align256((size_t)n * 4);
    int*   rowptr   = (int*)ws;    ws += align256((size_t)(n + 1) * 4);
    float* Bmat     = (float*)ws;  ws += align256((size_t)256 * 128 * 4);
    float* cvec     = (float*)ws;  ws += align256((size_t)128 * 4);
    int*   csr_src  = (int*)ws;    ws += align256((size_t)e * 4);

    // zero degree histograms + cursors (contiguous: dego, degi, cursor)
    hipMemsetAsync(dego, 0, align256((size_t)n * 4) * 3, stream);

    degree_kernel<<<2048, 256, 0, stream>>>(src, dst, dego, degi, e);
    norm_kernel<<<(n + 255) / 256, 256, 0, stream>>>(dego, degi, norm_out, norm_in, n);
    scan_kernel<<<1, 1024, 0, stream>>>(degi, rowptr, n);
    fill_kernel<<<2048, 256, 0, stream>>>(src, dst, rowptr, cursor, csr_src, e);
    prep_kernel<<<128, 128, 0, stream>>>(gcw, gcb, tcn, tcnb, Bmat, cvec);
    gather_kernel<<<2048, 256, 0, stream>>>(x, csr_src, rowptr, norm_out, norm_in, out, n);
    gemm_kernel<<<(n + 63) / 64, 256, 0, stream>>>(hist2, out, Bmat, cvec, n);
}

// Round 4
// 680.081 us; speedup vs baseline: 2.5213x; 1.1730x over previous
//
#include <hip/hip_runtime.h>

// out = hist2 @ K0^T + (norm_in ⊙ agg) @ (gc_weight @ K1^T) + c
// agg[d] = sum_{e: dst[e]=d} norm_out[src[e]] * x[src[e]]
// Round 4: replace single-block scan (162 µs, 1 CU) with hierarchical 3-pass scan.

__global__ void degree_kernel(const int* __restrict__ src, const int* __restrict__ dst,
                              int* __restrict__ dego, int* __restrict__ degi, int n_edges) {
    int stride = gridDim.x * blockDim.x;
    for (int i = blockIdx.x * blockDim.x + threadIdx.x; i < n_edges; i += stride) {
        atomicAdd(&dego[src[i]], 1);
        atomicAdd(&degi[dst[i]], 1);
    }
}

__global__ void norm_kernel(const int* __restrict__ dego, const int* __restrict__ degi,
                            float* __restrict__ norm_out, float* __restrict__ norm_in, int n) {
    int i = blockIdx.x * blockDim.x + threadIdx.x;
    if (i < n) {
        norm_out[i] = rsqrtf(fmaxf((float)dego[i], 1.0f));
        norm_in[i]  = rsqrtf(fmaxf((float)degi[i], 1.0f));
    }
}

// --- hierarchical scan: 1024 elements per block, 4 per thread ---

__global__ __launch_bounds__(256) void scan1_kernel(const int* __restrict__ degi,
                                                    int* __restrict__ partials, int n) {
    __shared__ int red[256];
    const int t = threadIdx.x;
    const int base = blockIdx.x * 1024 + t * 4;
    int s = 0;
    if (base + 3 < n) {
        int4 v = *reinterpret_cast<const int4*>(degi + base);
        s = v.x + v.y + v.z + v.w;
    } else {
        for (int j = 0; j < 4; ++j)
            if (base + j < n) s += degi[base + j];
    }
    red[t] = s;
    __syncthreads();
    for (int off = 128; off > 0; off >>= 1) {
        if (t < off) red[t] += red[t + off];
        __syncthreads();
    }
    if (t == 0) partials[blockIdx.x] = red[0];
}

// exclusive-scan partials in place; write grand total to rowptr[n]
__global__ __launch_bounds__(256) void scan2_kernel(int* __restrict__ partials, int nb,
                                                    int* __restrict__ rowptr, int n) {
    __shared__ int sums[256];
    const int t = threadIdx.x;
    sums[t] = (t < nb) ? partials[t] : 0;
    __syncthreads();
    for (int off = 1; off < 256; off <<= 1) {
        int v = (t >= off) ? sums[t - off] : 0;
        __syncthreads();
        if (t >= off) sums[t] += v;
        __syncthreads();
    }
    if (t < nb) partials[t] = (t == 0) ? 0 : sums[t - 1];
    if (t == 0) rowptr[n] = sums[nb - 1];
}

__global__ __launch_bounds__(256) void scan3_kernel(const int* __restrict__ degi,
                                                    const int* __restrict__ partials,
                                                    int* __restrict__ rowptr, int n) {
    __shared__ int tsum[256];
    const int t = threadIdx.x;
    const int base = blockIdx.x * 1024 + t * 4;
    int v0 = 0, v1 = 0, v2 = 0, v3 = 0;
    if (base + 3 < n) {
        int4 v = *reinterpret_cast<const int4*>(degi + base);
        v0 = v.x; v1 = v.y; v2 = v.z; v3 = v.w;
    } else {
        if (base + 0 < n) v0 = degi[base + 0];
        if (base + 1 < n) v1 = degi[base + 1];
        if (base + 2 < n) v2 = degi[base + 2];
    }
    tsum[t] = v0 + v1 + v2 + v3;
    __syncthreads();
    for (int off = 1; off < 256; off <<= 1) {
        int v = (t >= off) ? tsum[t - off] : 0;
        __syncthreads();
        if (t >= off) tsum[t] += v;
        __syncthreads();
    }
    int p0 = partials[blockIdx.x] + ((t == 0) ? 0 : tsum[t - 1]);
    int p1 = p0 + v0, p2 = p1 + v1, p3 = p2 + v2;
    if (base + 3 < n) {
        *reinterpret_cast<int4*>(rowptr + base) = make_int4(p0, p1, p2, p3);
    } else {
        if (base + 0 < n) rowptr[base + 0] = p0;
        if (base + 1 < n) rowptr[base + 1] = p1;
        if (base + 2 < n) rowptr[base + 2] = p2;
    }
}

// csr_src[rowptr[dst[e]] + k] = src[e]
__global__ void fill_kernel(const int* __restrict__ src, const int* __restrict__ dst,
                            const int* __restrict__ rowptr, int* __restrict__ cursor,
                            int* __restrict__ csr_src, int n_edges) {
    int stride = gridDim.x * blockDim.x;
    for (int i = blockIdx.x * blockDim.x + threadIdx.x; i < n_edges; i += stride) {
        int d = dst[i];
        int ofs = atomicAdd(&cursor[d], 1);
        csr_src[rowptr[d] + ofs] = src[i];
    }
}

// One wave per dst node; lane owns 2 consecutive floats. Writes norm_in-scaled agg.
__global__ void gather_kernel(const float* __restrict__ x, const int* __restrict__ csr_src,
                              const int* __restrict__ rowptr, const float* __restrict__ norm_out,
                              const float* __restrict__ norm_in, float* __restrict__ agg, int n) {
    int gtid = blockIdx.x * blockDim.x + threadIdx.x;
    int wave = gtid >> 6;
    int lane = threadIdx.x & 63;
    int n_waves = (gridDim.x * blockDim.x) >> 6;
    for (int d = wave; d < n; d += n_waves) {
        int s0 = rowptr[d];
        int s1 = rowptr[d + 1];
        float2 acc0 = {0.f, 0.f}, acc1 = {0.f, 0.f};
        int i = s0;
        for (; i + 1 < s1; i += 2) {
            int sa = csr_src[i];
            int sb = csr_src[i + 1];
            float na = norm_out[sa];
            float nb = norm_out[sb];
            float2 va = *reinterpret_cast<const float2*>(x + (size_t)sa * 128 + lane * 2);
            float2 vb = *reinterpret_cast<const float2*>(x + (size_t)sb * 128 + lane * 2);
            acc0.x = fmaf(va.x, na, acc0.x);
            acc0.y = fmaf(va.y, na, acc0.y);
            acc1.x = fmaf(vb.x, nb, acc1.x);
            acc1.y = fmaf(vb.y, nb, acc1.y);
        }
        if (i < s1) {
            int sa = csr_src[i];
            float na = norm_out[sa];
            float2 va = *reinterpret_cast<const float2*>(x + (size_t)sa * 128 + lane * 2);
            acc0.x = fmaf(va.x, na, acc0.x);
            acc0.y = fmaf(va.y, na, acc0.y);
        }
        float ni = norm_in[d];
        float2 r = {(acc0.x + acc1.x) * ni, (acc0.y + acc1.y) * ni};
        *reinterpret_cast<float2*>(agg + (size_t)d * 128 + lane * 2) = r;
    }
}

// Bmat[i][o] = K0[o,i]; Bmat[128+i][o] = sum_j gcw[i,j]*K1[o,j]; cvec[o] = tcnb[o] + K1[o,:]·gcb
__global__ void prep_kernel(const float* __restrict__ gcw, const float* __restrict__ gcb,
                            const float* __restrict__ tcn, const float* __restrict__ tcnb,
                            float* __restrict__ Bmat, float* __restrict__ cvec) {
    int i = blockIdx.x;
    int o = threadIdx.x;
    float m = 0.f;
    for (int j = 0; j < 128; ++j)
        m += gcw[i * 128 + j] * tcn[o * 384 + j * 3 + 1];
    Bmat[(128 + i) * 128 + o] = m;
    Bmat[i * 128 + o] = tcn[o * 384 + i * 3 + 0];
    if (i == 0) {
        float c = tcnb[o];
        for (int j = 0; j < 128; ++j)
            c += tcn[o * 384 + j * 3 + 1] * gcb[j];
        cvec[o] = c;
    }
}

// out[n,o] = cvec[o] + sum_i hist2[n,i]*Bmat[i][o] + sum_i agg[n,i]*Bmat[128+i][o]
// agg lives in d_out, overwritten in place by this block's rows.
__global__ __launch_bounds__(256) void gemm_kernel(const float* __restrict__ hist2,
                                                   float* __restrict__ outagg,
                                                   const float* __restrict__ Bmat,
                                                   const float* __restrict__ cvec, int n) {
    __shared__ float As[64][17];
    __shared__ float Bs[16][128];
    const int t = threadIdx.x;
    const int tcol = t & 15;
    const int trow = t >> 4;
    const int block_row = blockIdx.x * 64;

    float acc[4][8];
#pragma unroll
    for (int j = 0; j < 4; ++j)
#pragma unroll
        for (int m = 0; m < 8; ++m) acc[j][m] = 0.f;

    for (int kk = 0; kk < 256; kk += 16) {
        {
            int r = t >> 2;
            int k4 = (t & 3) << 2;
            int row = block_row + r;
            float4 v = make_float4(0.f, 0.f, 0.f, 0.f);
            if (row < n) {
                if (kk < 128)
                    v = *reinterpret_cast<const float4*>(hist2 + (size_t)row * 128 + kk + k4);
                else
                    v = *reinterpret_cast<const float4*>(outagg + (size_t)row * 128 + (kk - 128) + k4);
            }
            As[r][k4 + 0] = v.x; As[r][k4 + 1] = v.y;
            As[r][k4 + 2] = v.z; As[r][k4 + 3] = v.w;
        }
        {
#pragma unroll
            for (int rep = 0; rep < 2; ++rep) {
                int idx = t + rep * 256;
                int k = idx >> 5;
                int o4 = (idx & 31) << 2;
                const float4 v = *reinterpret_cast<const float4*>(Bmat + (size_t)(kk + k) * 128 + o4);
                *reinterpret_cast<float4*>(&Bs[k][o4]) = v;
            }
        }
        __syncthreads();
#pragma unroll
        for (int k = 0; k < 16; ++k) {
            float a0 = As[trow * 4 + 0][k];
            float a1 = As[trow * 4 + 1][k];
            float a2 = As[trow * 4 + 2][k];
            float a3 = As[trow * 4 + 3][k];
            float4 b0 = *reinterpret_cast<const float4*>(&Bs[k][tcol * 8]);
            float4 b1 = *reinterpret_cast<const float4*>(&Bs[k][tcol * 8 + 4]);
            float b[8] = {b0.x, b0.y, b0.z, b0.w, b1.x, b1.y, b1.z, b1.w};
#pragma unroll
            for (int m = 0; m < 8; ++m) {
                acc[0][m] = fmaf(a0, b[m], acc[0][m]);
                acc[1][m] = fmaf(a1, b[m], acc[1][m]);
                acc[2][m] = fmaf(a2, b[m], acc[2][m]);
                acc[3][m] = fmaf(a3, b[m], acc[3][m]);
            }
        }
        __syncthreads();
    }
    float cv[8];
#pragma unroll
    for (int m = 0; m < 8; ++m) cv[m] = cvec[tcol * 8 + m];
#pragma unroll
    for (int j = 0; j < 4; ++j) {
        int row = block_row + trow * 4 + j;
        if (row < n) {
            float4 w0 = make_float4(acc[j][0] + cv[0], acc[j][1] + cv[1],
                                    acc[j][2] + cv[2], acc[j][3] + cv[3]);
            float4 w1 = make_float4(acc[j][4] + cv[4], acc[j][5] + cv[5],
                                    acc[j][6] + cv[6], acc[j][7] + cv[7]);
            *reinterpret_cast<float4*>(outagg + (size_t)row * 128 + tcol * 8) = w0;
            *reinterpret_cast<float4*>(outagg + (size_t)row * 128 + tcol * 8 + 4) = w1;
        }
    }
}

extern "C" void kernel_launch(void* const* d_in, const int* in_sizes, int n_in,
                              void* d_out, int out_size, void* d_ws, size_t ws_size,
                              hipStream_t stream) {
    const float* x     = (const float*)d_in[0];
    const float* gcw   = (const float*)d_in[1];
    const float* gcb   = (const float*)d_in[2];
    const float* tcn   = (const float*)d_in[3];
    const float* tcnb  = (const float*)d_in[4];
    const float* hist2 = (const float*)d_in[7];   // hist0/hist1 are dead
    const int*   src   = (const int*)d_in[8];
    const int*   dst   = (const int*)d_in[9];
    float* out = (float*)d_out;

    const int n = in_sizes[0] / 128;
    const int e = in_sizes[8];
    const int nb = (n + 1023) / 1024;   // scan blocks (98 for n=100000; must be <=256)

    auto align256 = [](size_t v) { return (v + 255) & ~(size_t)255; };
    char* ws = (char*)d_ws;
    int*   dego     = (int*)ws;    ws += align256((size_t)n * 4);
    int*   degi     = (int*)ws;    ws += align256((size_t)n * 4);
    int*   cursor   = (int*)ws;    ws += align256((size_t)n * 4);
    float* norm_out = (float*)ws;  ws += align256((size_t)n * 4);
    float* norm_in  = (float*)ws;  ws += align256((size_t)n * 4);
    int*   rowptr   = (int*)ws;    ws += align256((size_t)(n + 1) * 4);
    int*   partials = (int*)ws;    ws += align256((size_t)256 * 4);
    float* Bmat     = (float*)ws;  ws += align256((size_t)256 * 128 * 4);
    float* cvec     = (float*)ws;  ws += align256((size_t)128 * 4);
    int*   csr_src  = (int*)ws;    ws += align256((size_t)e * 4);

    // zero degree histograms + cursors (contiguous: dego, degi, cursor)
    hipMemsetAsync(dego, 0, align256((size_t)n * 4) * 3, stream);

    degree_kernel<<<2048, 256, 0, stream>>>(src, dst, dego, degi, e);
    norm_kernel<<<(n + 255) / 256, 256, 0, stream>>>(dego, degi, norm_out, norm_in, n);
    scan1_kernel<<<nb, 256, 0, stream>>>(degi, partials, n);
    scan2_kernel<<<1, 256, 0, stream>>>(partials, nb, rowptr, n);
    scan3_kernel<<<nb, 256, 0, stream>>>(degi, partials, rowptr, n);
    fill_kernel<<<2048, 256, 0, stream>>>(src, dst, rowptr, cursor, csr_src, e);
    prep_kernel<<<128, 128, 0, stream>>>(gcw, gcb, tcn, tcnb, Bmat, cvec);
    gather_kernel<<<2048, 256, 0, stream>>>(x, csr_src, rowptr, norm_out, norm_in, out, n);
    gemm_kernel<<<(n + 63) / 64, 256, 0, stream>>>(hist2, out, Bmat, cvec, n);
}

// Round 5
// 674.960 us; speedup vs baseline: 2.5404x; 1.0076x over previous
//
#include <hip/hip_runtime.h>

// out = hist2 @ K0^T + (norm_in ⊙ agg) @ (gc_weight @ K1^T) + c
// agg[d] = sum_{e: dst[e]=d} norm_out[src[e]] * x[src[e]]
// Round 5: gather unroll-4 (2x memory-level parallelism), absolute-cursor fill.

__global__ void degree_kernel(const int* __restrict__ src, const int* __restrict__ dst,
                              int* __restrict__ dego, int* __restrict__ degi, int n_edges) {
    int stride = gridDim.x * blockDim.x;
    for (int i = blockIdx.x * blockDim.x + threadIdx.x; i < n_edges; i += stride) {
        atomicAdd(&dego[src[i]], 1);
        atomicAdd(&degi[dst[i]], 1);
    }
}

__global__ void norm_kernel(const int* __restrict__ dego, const int* __restrict__ degi,
                            float* __restrict__ norm_out, float* __restrict__ norm_in, int n) {
    int i = blockIdx.x * blockDim.x + threadIdx.x;
    if (i < n) {
        norm_out[i] = rsqrtf(fmaxf((float)dego[i], 1.0f));
        norm_in[i]  = rsqrtf(fmaxf((float)degi[i], 1.0f));
    }
}

// --- hierarchical scan: 1024 elements per block, 4 per thread ---

__global__ __launch_bounds__(256) void scan1_kernel(const int* __restrict__ degi,
                                                    int* __restrict__ partials, int n) {
    __shared__ int red[256];
    const int t = threadIdx.x;
    const int base = blockIdx.x * 1024 + t * 4;
    int s = 0;
    if (base + 3 < n) {
        int4 v = *reinterpret_cast<const int4*>(degi + base);
        s = v.x + v.y + v.z + v.w;
    } else {
        for (int j = 0; j < 4; ++j)
            if (base + j < n) s += degi[base + j];
    }
    red[t] = s;
    __syncthreads();
    for (int off = 128; off > 0; off >>= 1) {
        if (t < off) red[t] += red[t + off];
        __syncthreads();
    }
    if (t == 0) partials[blockIdx.x] = red[0];
}

__global__ __launch_bounds__(256) void scan2_kernel(int* __restrict__ partials, int nb,
                                                    int* __restrict__ rowptr, int n) {
    __shared__ int sums[256];
    const int t = threadIdx.x;
    sums[t] = (t < nb) ? partials[t] : 0;
    __syncthreads();
    for (int off = 1; off < 256; off <<= 1) {
        int v = (t >= off) ? sums[t - off] : 0;
        __syncthreads();
        if (t >= off) sums[t] += v;
        __syncthreads();
    }
    if (t < nb) partials[t] = (t == 0) ? 0 : sums[t - 1];
    if (t == 0) rowptr[n] = sums[nb - 1];
}

__global__ __launch_bounds__(256) void scan3_kernel(const int* __restrict__ degi,
                                                    const int* __restrict__ partials,
                                                    int* __restrict__ rowptr, int n) {
    __shared__ int tsum[256];
    const int t = threadIdx.x;
    const int base = blockIdx.x * 1024 + t * 4;
    int v0 = 0, v1 = 0, v2 = 0, v3 = 0;
    if (base + 3 < n) {
        int4 v = *reinterpret_cast<const int4*>(degi + base);
        v0 = v.x; v1 = v.y; v2 = v.z; v3 = v.w;
    } else {
        if (base + 0 < n) v0 = degi[base + 0];
        if (base + 1 < n) v1 = degi[base + 1];
        if (base + 2 < n) v2 = degi[base + 2];
    }
    tsum[t] = v0 + v1 + v2 + v3;
    __syncthreads();
    for (int off = 1; off < 256; off <<= 1) {
        int v = (t >= off) ? tsum[t - off] : 0;
        __syncthreads();
        if (t >= off) tsum[t] += v;
        __syncthreads();
    }
    int p0 = partials[blockIdx.x] + ((t == 0) ? 0 : tsum[t - 1]);
    int p1 = p0 + v0, p2 = p1 + v1, p3 = p2 + v2;
    if (base + 3 < n) {
        *reinterpret_cast<int4*>(rowptr + base) = make_int4(p0, p1, p2, p3);
    } else {
        if (base + 0 < n) rowptr[base + 0] = p0;
        if (base + 1 < n) rowptr[base + 1] = p1;
        if (base + 2 < n) rowptr[base + 2] = p2;
    }
}

// cursor pre-initialized to rowptr: atomicAdd gives the absolute csr slot.
__global__ void fill_kernel(const int* __restrict__ src, const int* __restrict__ dst,
                            int* __restrict__ cursor, int* __restrict__ csr_src, int n_edges) {
    int stride = gridDim.x * blockDim.x;
    for (int i = blockIdx.x * blockDim.x + threadIdx.x; i < n_edges; i += stride) {
        int pos = atomicAdd(&cursor[dst[i]], 1);
        csr_src[pos] = src[i];
    }
}

// One wave per dst node; lane owns 2 consecutive floats; 4 edges in flight.
__global__ void gather_kernel(const float* __restrict__ x, const int* __restrict__ csr_src,
                              const int* __restrict__ rowptr, const float* __restrict__ norm_out,
                              const float* __restrict__ norm_in, float* __restrict__ agg, int n) {
    int gtid = blockIdx.x * blockDim.x + threadIdx.x;
    int wave = gtid >> 6;
    int lane = threadIdx.x & 63;
    int n_waves = (gridDim.x * blockDim.x) >> 6;
    for (int d = wave; d < n; d += n_waves) {
        int s0 = rowptr[d];
        int s1 = rowptr[d + 1];
        float2 a0 = {0.f, 0.f}, a1 = {0.f, 0.f}, a2 = {0.f, 0.f}, a3 = {0.f, 0.f};
        int i = s0;
        for (; i + 3 < s1; i += 4) {
            int sa = csr_src[i + 0];
            int sb = csr_src[i + 1];
            int sc = csr_src[i + 2];
            int sd = csr_src[i + 3];
            float na = norm_out[sa];
            float nb = norm_out[sb];
            float nc = norm_out[sc];
            float nd = norm_out[sd];
            float2 va = *reinterpret_cast<const float2*>(x + (size_t)sa * 128 + lane * 2);
            float2 vb = *reinterpret_cast<const float2*>(x + (size_t)sb * 128 + lane * 2);
            float2 vc = *reinterpret_cast<const float2*>(x + (size_t)sc * 128 + lane * 2);
            float2 vd = *reinterpret_cast<const float2*>(x + (size_t)sd * 128 + lane * 2);
            a0.x = fmaf(va.x, na, a0.x); a0.y = fmaf(va.y, na, a0.y);
            a1.x = fmaf(vb.x, nb, a1.x); a1.y = fmaf(vb.y, nb, a1.y);
            a2.x = fmaf(vc.x, nc, a2.x); a2.y = fmaf(vc.y, nc, a2.y);
            a3.x = fmaf(vd.x, nd, a3.x); a3.y = fmaf(vd.y, nd, a3.y);
        }
        for (; i < s1; ++i) {
            int sa = csr_src[i];
            float na = norm_out[sa];
            float2 va = *reinterpret_cast<const float2*>(x + (size_t)sa * 128 + lane * 2);
            a0.x = fmaf(va.x, na, a0.x); a0.y = fmaf(va.y, na, a0.y);
        }
        float ni = norm_in[d];
        float2 r = {(a0.x + a1.x + a2.x + a3.x) * ni,
                    (a0.y + a1.y + a2.y + a3.y) * ni};
        *reinterpret_cast<float2*>(agg + (size_t)d * 128 + lane * 2) = r;
    }
}

// Bmat[i][o] = K0[o,i]; Bmat[128+i][o] = sum_j gcw[i,j]*K1[o,j]; cvec[o] = tcnb[o] + K1[o,:]·gcb
__global__ void prep_kernel(const float* __restrict__ gcw, const float* __restrict__ gcb,
                            const float* __restrict__ tcn, const float* __restrict__ tcnb,
                            float* __restrict__ Bmat, float* __restrict__ cvec) {
    int i = blockIdx.x;
    int o = threadIdx.x;
    float m = 0.f;
    for (int j = 0; j < 128; ++j)
        m += gcw[i * 128 + j] * tcn[o * 384 + j * 3 + 1];
    Bmat[(128 + i) * 128 + o] = m;
    Bmat[i * 128 + o] = tcn[o * 384 + i * 3 + 0];
    if (i == 0) {
        float c = tcnb[o];
        for (int j = 0; j < 128; ++j)
            c += tcn[o * 384 + j * 3 + 1] * gcb[j];
        cvec[o] = c;
    }
}

// out[n,o] = cvec[o] + sum_i hist2[n,i]*Bmat[i][o] + sum_i agg[n,i]*Bmat[128+i][o]
__global__ __launch_bounds__(256) void gemm_kernel(const float* __restrict__ hist2,
                                                   float* __restrict__ outagg,
                                                   const float* __restrict__ Bmat,
                                                   const float* __restrict__ cvec, int n) {
    __shared__ float As[64][17];
    __shared__ float Bs[16][128];
    const int t = threadIdx.x;
    const int tcol = t & 15;
    const int trow = t >> 4;
    const int block_row = blockIdx.x * 64;

    float acc[4][8];
#pragma unroll
    for (int j = 0; j < 4; ++j)
#pragma unroll
        for (int m = 0; m < 8; ++m) acc[j][m] = 0.f;

    for (int kk = 0; kk < 256; kk += 16) {
        {
            int r = t >> 2;
            int k4 = (t & 3) << 2;
            int row = block_row + r;
            float4 v = make_float4(0.f, 0.f, 0.f, 0.f);
            if (row < n) {
                if (kk < 128)
                    v = *reinterpret_cast<const float4*>(hist2 + (size_t)row * 128 + kk + k4);
                else
                    v = *reinterpret_cast<const float4*>(outagg + (size_t)row * 128 + (kk - 128) + k4);
            }
            As[r][k4 + 0] = v.x; As[r][k4 + 1] = v.y;
            As[r][k4 + 2] = v.z; As[r][k4 + 3] = v.w;
        }
        {
#pragma unroll
            for (int rep = 0; rep < 2; ++rep) {
                int idx = t + rep * 256;
                int k = idx >> 5;
                int o4 = (idx & 31) << 2;
                const float4 v = *reinterpret_cast<const float4*>(Bmat + (size_t)(kk + k) * 128 + o4);
                *reinterpret_cast<float4*>(&Bs[k][o4]) = v;
            }
        }
        __syncthreads();
#pragma unroll
        for (int k = 0; k < 16; ++k) {
            float a0 = As[trow * 4 + 0][k];
            float a1 = As[trow * 4 + 1][k];
            float a2 = As[trow * 4 + 2][k];
            float a3 = As[trow * 4 + 3][k];
            float4 b0 = *reinterpret_cast<const float4*>(&Bs[k][tcol * 8]);
            float4 b1 = *reinterpret_cast<const float4*>(&Bs[k][tcol * 8 + 4]);
            float b[8] = {b0.x, b0.y, b0.z, b0.w, b1.x, b1.y, b1.z, b1.w};
#pragma unroll
            for (int m = 0; m < 8; ++m) {
                acc[0][m] = fmaf(a0, b[m], acc[0][m]);
                acc[1][m] = fmaf(a1, b[m], acc[1][m]);
                acc[2][m] = fmaf(a2, b[m], acc[2][m]);
                acc[3][m] = fmaf(a3, b[m], acc[3][m]);
            }
        }
        __syncthreads();
    }
    float cv[8];
#pragma unroll
    for (int m = 0; m < 8; ++m) cv[m] = cvec[tcol * 8 + m];
#pragma unroll
    for (int j = 0; j < 4; ++j) {
        int row = block_row + trow * 4 + j;
        if (row < n) {
            float4 w0 = make_float4(acc[j][0] + cv[0], acc[j][1] + cv[1],
                                    acc[j][2] + cv[2], acc[j][3] + cv[3]);
            float4 w1 = make_float4(acc[j][4] + cv[4], acc[j][5] + cv[5],
                                    acc[j][6] + cv[6], acc[j][7] + cv[7]);
            *reinterpret_cast<float4*>(outagg + (size_t)row * 128 + tcol * 8) = w0;
            *reinterpret_cast<float4*>(outagg + (size_t)row * 128 + tcol * 8 + 4) = w1;
        }
    }
}

extern "C" void kernel_launch(void* const* d_in, const int* in_sizes, int n_in,
                              void* d_out, int out_size, void* d_ws, size_t ws_size,
                              hipStream_t stream) {
    const float* x     = (const float*)d_in[0];
    const float* gcw   = (const float*)d_in[1];
    const float* gcb   = (const float*)d_in[2];
    const float* tcn   = (const float*)d_in[3];
    const float* tcnb  = (const float*)d_in[4];
    const float* hist2 = (const float*)d_in[7];   // hist0/hist1 are dead
    const int*   src   = (const int*)d_in[8];
    const int*   dst   = (const int*)d_in[9];
    float* out = (float*)d_out;

    const int n = in_sizes[0] / 128;
    const int e = in_sizes[8];
    const int nb = (n + 1023) / 1024;   // scan blocks (98 for n=100000; must be <=256)

    auto align256 = [](size_t v) { return (v + 255) & ~(size_t)255; };
    char* ws = (char*)d_ws;
    int*   dego     = (int*)ws;    ws += align256((size_t)n * 4);
    int*   degi     = (int*)ws;    ws += align256((size_t)n * 4);
    int*   cursor   = (int*)ws;    ws += align256((size_t)n * 4);
    float* norm_out = (float*)ws;  ws += align256((size_t)n * 4);
    float* norm_in  = (float*)ws;  ws += align256((size_t)n * 4);
    int*   rowptr   = (int*)ws;    ws += align256((size_t)(n + 1) * 4);
    int*   partials = (int*)ws;    ws += align256((size_t)256 * 4);
    float* Bmat     = (float*)ws;  ws += align256((size_t)256 * 128 * 4);
    float* cvec     = (float*)ws;  ws += align256((size_t)128 * 4);
    int*   csr_src  = (int*)ws;    ws += align256((size_t)e * 4);

    // zero degree histograms (dego, degi contiguous)
    hipMemsetAsync(dego, 0, align256((size_t)n * 4) * 2, stream);

    degree_kernel<<<2048, 256, 0, stream>>>(src, dst, dego, degi, e);
    norm_kernel<<<(n + 255) / 256, 256, 0, stream>>>(dego, degi, norm_out, norm_in, n);
    scan1_kernel<<<nb, 256, 0, stream>>>(degi, partials, n);
    scan2_kernel<<<1, 256, 0, stream>>>(partials, nb, rowptr, n);
    scan3_kernel<<<nb, 256, 0, stream>>>(degi, partials, rowptr, n);
    hipMemcpyAsync(cursor, rowptr, (size_t)n * 4, hipMemcpyDeviceToDevice, stream);
    fill_kernel<<<2048, 256, 0, stream>>>(src, dst, cursor, csr_src, e);
    prep_kernel<<<128, 128, 0, stream>>>(gcw, gcb, tcn, tcnb, Bmat, cvec);
    gather_kernel<<<2048, 256, 0, stream>>>(x, csr_src, rowptr, norm_out, norm_in, out, n);
    gemm_kernel<<<(n + 63) / 64, 256, 0, stream>>>(hist2, out, Bmat, cvec, n);
}